// Round 9
// baseline (106.071 us; speedup 1.0000x reference)
//
#include <hip/hip_runtime.h>

#define NTOK 32768
#define CDIM 256
#define KCODE 1024
#define C4 64   // CDIM/4

typedef __bf16 bf16x8 __attribute__((ext_vector_type(8)));
typedef float  f32x4  __attribute__((ext_vector_type(4)));
typedef const __attribute__((address_space(1))) void* as1cvp;
typedef __attribute__((address_space(3))) void* as3vp;

__device__ __forceinline__ unsigned long long umin64(unsigned long long a, unsigned long long b) { return a < b ? a : b; }
__device__ __forceinline__ unsigned long long umax64(unsigned long long a, unsigned long long b) { return a > b ? a : b; }

// ---------------- K1: normalize codebook -> en fp32, en2, eh/el bf16 --------
__global__ void k_norm_emb(const float* __restrict__ emb,
                           float* __restrict__ en, float* __restrict__ en2,
                           __bf16* __restrict__ eh, __bf16* __restrict__ el) {
    int k = blockIdx.x;
    int l = threadIdx.x;               // 64 lanes, 4 floats each
    float4 v = reinterpret_cast<const float4*>(emb)[k * C4 + l];
    float ss = v.x*v.x + v.y*v.y + v.z*v.z + v.w*v.w;
    #pragma unroll
    for (int o = 32; o >= 1; o >>= 1) ss += __shfl_xor(ss, o, 64);
    float den = fmaxf(sqrtf(ss), 1e-12f);
    float4 e;
    e.x = v.x / den; e.y = v.y / den; e.z = v.z / den; e.w = v.w / den;
    reinterpret_cast<float4*>(en)[k * C4 + l] = e;
    float s2 = e.x*e.x + e.y*e.y + e.z*e.z + e.w*e.w;
    #pragma unroll
    for (int o = 32; o >= 1; o >>= 1) s2 += __shfl_xor(s2, o, 64);
    if (l == 0) en2[k] = s2;

    __bf16* ehp = eh + (size_t)k * CDIM + 4 * l;
    __bf16* elp = el + (size_t)k * CDIM + 4 * l;
    float ev[4] = {e.x, e.y, e.z, e.w};
    #pragma unroll
    for (int q = 0; q < 4; ++q) {
        __bf16 h = (__bf16)ev[q];
        ehp[q] = h;
        elp[q] = (__bf16)(ev[q] - (float)h);
    }
}

// ---------------- K2: transpose+normalize z -> znt fp32 + znt2 --------------
__global__ void k_norm_z(const float* __restrict__ z,
                         float* __restrict__ znt, float* __restrict__ znt2) {
    __shared__ float zsb[CDIM * 32];   // 32 KB, [c][ (tok+c)&31 ]
    __shared__ float ssp[256];
    __shared__ float dens[32];
    int tid = threadIdx.x;
    int t0  = blockIdx.x * 32;
    int n   = t0 >> 10;
    int thw0 = t0 & 1023;

    int l = tid & 31, grp = tid >> 5;          // 8 c-stripes
    const float* zb = z + (((size_t)(n * CDIM)) << 10) + thw0 + l;
    float ss = 0.f;
    int c0 = grp * 32;
    for (int cc = 0; cc < 32; ++cc) {
        int c = c0 + cc;
        float v = zb[((size_t)c) << 10];
        zsb[c * 32 + ((l + c) & 31)] = v;
        ss += v * v;
    }
    ssp[tid] = ss;
    __syncthreads();
    if (tid < 32) {
        float tot = 0.f;
        #pragma unroll
        for (int g = 0; g < 8; ++g) tot += ssp[g * 32 + tid];
        dens[tid] = fmaxf(sqrtf(tot), 1e-12f);
    }
    __syncthreads();

    int l2 = tid & 63, tg = tid >> 6;          // 4 token-groups of 8
    for (int it = 0; it < 8; ++it) {
        int tok = tg * 8 + it;
        float den = dens[tok];
        float s2 = 0.f;
        #pragma unroll
        for (int cq = 0; cq < 4; ++cq) {
            int c = cq * 64 + l2;
            float v = zsb[c * 32 + ((tok + c) & 31)] / den;
            znt[((size_t)(t0 + tok)) * CDIM + c] = v;
            s2 += v * v;
        }
        #pragma unroll
        for (int o = 32; o >= 1; o >>= 1) s2 += __shfl_xor(s2, o, 64);
        if (l2 == 0) znt2[t0 + tok] = s2;
    }
}

// ---------------- K3: MFMA GEMM + top-2 + fused fixup + fused gather --------
// 512 blocks x 512 threads (8 waves: 4M x 2N), BM=64, ~72KB LDS ->
// 2 blocks/CU = 16 waves/CU (4/SIMD) for latency hiding. Per wave: 16 tokens
// x 16 codes, A (fp32->hi/lo split) 64 VGPR. __launch_bounds__(512,4) caps
// VGPR at 128 (est ~117, no spill). B double-buffered via global_load_lds.
__global__ __launch_bounds__(512, 4) void k_mfma(
        const float* __restrict__ znt,
        const __bf16* __restrict__ eh, const __bf16* __restrict__ el,
        const float* __restrict__ en2g,
        const float* __restrict__ znt2, const float* __restrict__ en,
        const float* __restrict__ emb, float* __restrict__ out) {
    // union: [0,65536) ebuf | [65536,69632) en2s ; gather reuses [0,65792) as qt[64][257]
    __shared__ __align__(16) char smem_u[69632];
    __shared__ unsigned long long t2l[64][2][2];
    __shared__ int idxs[64];
    __bf16* ebuf = reinterpret_cast<__bf16*>(smem_u);            // [2][2][8192]
    float*  en2s = reinterpret_cast<float*>(smem_u + 65536);     // [1024]
    float*  qt   = reinterpret_cast<float*>(smem_u);             // [64][257]

    int tid = threadIdx.x;
    int l = tid & 63, wid = tid >> 6;
    int mw = wid >> 1, nw = wid & 1;           // 4M x 2N
    int t0 = blockIdx.x * 64;
    int row = l & 15, kg = l >> 4;             // frag row / k-group

    for (int i = tid; i < KCODE; i += 512) en2s[i] = en2g[i];

    // hoist A from fp32 znt, split hi/lo: 8 ks x {h,l} = 64 VGPR per wave
    bf16x8 ah[8], al_[8];
    {
        size_t tok = (size_t)(t0 + mw * 16 + row);
        const float* pz = znt + tok * CDIM + kg * 8;
        #pragma unroll
        for (int ks = 0; ks < 8; ++ks) {
            float f[8];
            *reinterpret_cast<float4*>(&f[0]) = *reinterpret_cast<const float4*>(pz + ks * 32);
            *reinterpret_cast<float4*>(&f[4]) = *reinterpret_cast<const float4*>(pz + ks * 32 + 4);
            bf16x8 h, lo;
            #pragma unroll
            for (int q = 0; q < 8; ++q) {
                __bf16 hv = (__bf16)f[q];
                h[q] = hv;
                lo[q] = (__bf16)(f[q] - (float)hv);
            }
            ah[ks] = h; al_[ks] = lo;
        }
    }

    // top-2 keys per lane: 4 token-rows
    unsigned long long b1[4], b2[4];
    #pragma unroll
    for (int i = 0; i < 4; ++i) { b1[i] = ~0ull; b2[i] = ~0ull; }

    // stage one 32-code chunk (hi+lo) with XOR swizzle (slot = c16 ^ (code&15))
    auto stage = [&](int buf, int ch) {
        #pragma unroll
        for (int a = 0; a < 2; ++a) {
            const __bf16* src = a ? el : eh;
            #pragma unroll
            for (int i2 = 0; i2 < 2; ++i2) {
                int s = i2 * 512 + tid;
                int code = s >> 5, c16 = s & 31;
                int gslot = c16 ^ (code & 15);
                const __bf16* gp = src + ((size_t)(ch * 32 + code)) * CDIM + gslot * 8;
                __bf16* ld = ebuf + (size_t)(buf * 2 + a) * 8192 + (size_t)(i2 * 512 + wid * 64) * 8;
                __builtin_amdgcn_global_load_lds((as1cvp)gp, (as3vp)ld, 16, 0, 0);
            }
        }
    };

    stage(0, 0);
    __syncthreads();
    #pragma unroll 2
    for (int ch = 0; ch < 32; ++ch) {
        int cur = ch & 1;
        if (ch < 31) stage(cur ^ 1, ch + 1);

        const __bf16* bh_base = ebuf + (size_t)(cur * 2 + 0) * 8192;
        const __bf16* bl_base = ebuf + (size_t)(cur * 2 + 1) * 8192;

        f32x4 a0, a1, a2;
        #pragma unroll
        for (int r = 0; r < 4; ++r) { a0[r] = 0.f; a1[r] = 0.f; a2[r] = 0.f; }

        int code_l = nw * 16 + row;
        #pragma unroll
        for (int ks = 0; ks < 8; ++ks) {
            int slot = (ks * 4 + kg) ^ row;
            bf16x8 bh = *reinterpret_cast<const bf16x8*>(bh_base + code_l * 256 + slot * 8);
            bf16x8 bl = *reinterpret_cast<const bf16x8*>(bl_base + code_l * 256 + slot * 8);
            a0 = __builtin_amdgcn_mfma_f32_16x16x32_bf16(ah[ks],  bh, a0, 0, 0, 0);
            a1 = __builtin_amdgcn_mfma_f32_16x16x32_bf16(ah[ks],  bl, a1, 0, 0, 0);
            a2 = __builtin_amdgcn_mfma_f32_16x16x32_bf16(al_[ks], bh, a2, 0, 0, 0);
        }

        // selection epilogue: d' = e2 - 2*dot; code col = lane&15
        int code = ch * 32 + code_l;
        float e2v = en2s[code];
        #pragma unroll
        for (int r = 0; r < 4; ++r) {
            float d = fmaf(-2.0f, (a0[r] + a1[r]) + a2[r], e2v);
            unsigned ub = __float_as_uint(d);
            ub = (ub & 0x80000000u) ? ~ub : (ub | 0x80000000u);
            unsigned long long key = ((unsigned long long)ub << 32) | (unsigned)code;
            if (key < b1[r]) { b2[r] = b1[r]; b1[r] = key; }
            else if (key < b2[r]) { b2[r] = key; }
        }
        __syncthreads();
    }

    // butterfly top-2 merge across the 16 code-col lanes
    #pragma unroll
    for (int i = 0; i < 4; ++i) {
        #pragma unroll
        for (int off = 1; off < 16; off <<= 1) {
            unsigned long long o1 = __shfl_xor(b1[i], off, 16);
            unsigned long long o2 = __shfl_xor(b2[i], off, 16);
            unsigned long long m1 = umin64(b1[i], o1);
            unsigned long long m2 = umin64(umax64(b1[i], o1), umin64(b2[i], o2));
            b1[i] = m1; b2[i] = m2;
        }
    }
    if ((l & 15) == 0) {
        #pragma unroll
        for (int r = 0; r < 4; ++r) {
            int tl = mw * 16 + kg * 4 + r;     // C/D row = token row
            t2l[tl][nw][0] = b1[r];
            t2l[tl][nw][1] = b2[r];
        }
    }
    __syncthreads();

    // fused fp32 fixup: 8 threads per token, 32 dims each
    {
        int tl = tid >> 3, q = tid & 7;
        int t = t0 + tl;
        unsigned long long x1 = t2l[tl][0][0], x2 = t2l[tl][0][1];
        unsigned long long y1 = t2l[tl][1][0], y2 = t2l[tl][1][1];
        unsigned c1 = (unsigned)umin64(x1, y1);
        unsigned c2 = (unsigned)umin64(umax64(x1, y1), umin64(x2, y2));
        const float4* zp  = reinterpret_cast<const float4*>(znt) + (size_t)t  * C4 + q * 8;
        const float4* eap = reinterpret_cast<const float4*>(en)  + (size_t)c1 * C4 + q * 8;
        const float4* ebp = reinterpret_cast<const float4*>(en)  + (size_t)c2 * C4 + q * 8;
        float da = 0.f, db = 0.f;
        #pragma unroll
        for (int i = 0; i < 8; ++i) {
            float4 zv = zp[i], av = eap[i], bv = ebp[i];
            da += zv.x*av.x + zv.y*av.y + zv.z*av.z + zv.w*av.w;
            db += zv.x*bv.x + zv.y*bv.y + zv.z*bv.z + zv.w*bv.w;
        }
        da += __shfl_xor(da, 1, 8); da += __shfl_xor(da, 2, 8); da += __shfl_xor(da, 4, 8);
        db += __shfl_xor(db, 1, 8); db += __shfl_xor(db, 2, 8); db += __shfl_xor(db, 4, 8);
        if (q == 0) {
            float z2 = znt2[t];
            float d1 = (z2 + en2s[c1]) - 2.0f * da;
            float d2 = (z2 + en2s[c2]) - 2.0f * db;
            int k = (d2 < d1 || (d2 == d1 && c2 < c1)) ? (int)c2 : (int)c1;
            idxs[tl] = k;
            out[(size_t)NTOK * CDIM + t] = (float)k;   // index output tail
        }
    }
    __syncthreads();   // fixup reads of en2s done; idxs visible; qt may overwrite

    // fused gather stage: emb rows -> qt[64][257]; tl varies fastest (bank-safe)
    {
        int tl = tid & 63, q = tid >> 6;       // 8 c-segments of 32 floats
        int kidx = idxs[tl];
        const float4* ep = reinterpret_cast<const float4*>(emb + (size_t)kidx * CDIM + q * 32);
        #pragma unroll
        for (int i = 0; i < 8; ++i) {
            float4 v = ep[i];
            int cb = q * 32 + i * 4;
            qt[tl * 257 + cb + 0] = v.x;
            qt[tl * 257 + cb + 1] = v.y;
            qt[tl * 257 + cb + 2] = v.z;
            qt[tl * 257 + cb + 3] = v.w;
        }
    }
    __syncthreads();

    // transpose write: lanes = hw (coalesced 256B stores), NCHW
    {
        int hwo = tid & 63, cg = tid >> 6;     // 8 c-groups of 32
        int n = t0 >> 10, hw = (t0 & 1023) + hwo;
        float* ob = out + (size_t)n * (CDIM * 1024) + hw;
        #pragma unroll 8
        for (int cc = 0; cc < 32; ++cc) {
            int c = cg * 32 + cc;
            ob[(size_t)c * 1024] = qt[hwo * 257 + c];
        }
    }
}

extern "C" void kernel_launch(void* const* d_in, const int* in_sizes, int n_in,
                              void* d_out, int out_size, void* d_ws, size_t ws_size,
                              hipStream_t stream) {
    const float* z   = (const float*)d_in[0];
    const float* emb = (const float*)d_in[1];
    float* out  = (float*)d_out;

    float*  en   = (float*)d_ws;                        // 1 MB
    float*  en2  = en + (size_t)KCODE * CDIM;           // 4 KB
    float*  znt2 = en2 + KCODE;                         // 128 KB
    __bf16* eh   = (__bf16*)(znt2 + NTOK);              // 512 KB
    __bf16* el   = eh + (size_t)KCODE * CDIM;           // 512 KB
    float*  znt  = (float*)(el + (size_t)KCODE * CDIM); // 32 MB

    k_norm_emb<<<KCODE, 64, 0, stream>>>(emb, en, en2, eh, el);
    k_norm_z<<<NTOK / 32, 256, 0, stream>>>(z, znt, znt2);
    k_mfma<<<NTOK / 64, 512, 0, stream>>>(znt, eh, el, en2, znt2, en, emb, out);
}